// Round 4
// baseline (475.412 us; speedup 1.0000x reference)
//
#include <hip/hip_runtime.h>

// NearestEmbed: x (32,64,64,64) f32, weight (64,512) f32.
// Round 4: weight fetched via the SCALAR pipe (wave-uniform s_load_dwordx16)
// instead of broadcast ds_read_b128 — Round 3 counters showed the LDS pipe
// (per-CU, ~12cyc/b128) was the roofline at 260us while VALU sat at 33%.
// k-group of 16 keeps 16 independent FMA chains and amortizes min-tracking.

#define DD   64
#define HWSZ 4096            // H*W
#define NLOC (32 * HWSZ)     // 131072
#define KK   512
#define KG   16              // k-group: one 64B weight row segment per d
#define TAU  1e-3f

__global__ __launch_bounds__(256, 2)
void ne_kernel(const float* __restrict__ x, const float* __restrict__ w,
               float* __restrict__ out_res, float* __restrict__ out_idx) {
    __shared__ float w2lds[KK];      // 2 KB: ||e_k||^2

    const int tid = threadIdx.x;
    const int loc = blockIdx.x * 256 + tid;
    const int b   = loc >> 12;        // / 4096
    const int hw  = loc & 4095;
    const long base = (long)b * (DD * HWSZ) + hw;

    // ---- x vector into registers (coalesced per d) ----
    float xr[DD];
    #pragma unroll
    for (int d = 0; d < DD; ++d) xr[d] = x[base + (long)d * HWSZ];

    // ---- ||e_k||^2 into LDS (coalesced, L2-hot) ----
    #pragma unroll 1
    for (int k = tid; k < KK; k += 256) {
        float s = 0.f;
        #pragma unroll
        for (int d = 0; d < DD; ++d) { float v = w[d * KK + k]; s = fmaf(v, v, s); }
        w2lds[k] = s;
    }
    __syncthreads();

    // ---- main pass: weight rows via scalar loads, 16 acc chains ----
    float s1 = 3.4e38f, s2 = 3.4e38f, s3 = 3.4e38f;
    int   k1 = 0, k2 = 0, k3 = 0;

    #pragma unroll 1
    for (int kg = 0; kg < KK; kg += KG) {
        float acc[KG];
        #pragma unroll
        for (int j = 0; j < KG; ++j) acc[j] = 0.f;

        #pragma unroll
        for (int d = 0; d < DD; ++d) {
            const float* wrow = w + d * KK + kg;   // wave-uniform address -> s_load
            #pragma unroll
            for (int j = 0; j < KG; ++j)
                acc[j] = fmaf(xr[d], wrow[j], acc[j]);   // v_fma v,s,v
        }

        #pragma unroll
        for (int j = 0; j < KG; ++j) {
            float s  = fmaf(-2.f, acc[j], w2lds[kg + j]);
            int   kk = kg + j;
            bool c1 = s < s1, c2 = s < s2, c3 = s < s3;
            s3 = c2 ? s2 : (c3 ? s  : s3);
            k3 = c2 ? k2 : (c3 ? kk : k3);
            s2 = c1 ? s1 : (c2 ? s  : s2);
            k2 = c1 ? k1 : (c2 ? kk : k2);
            s1 = c1 ? s  : s1;
            k1 = c1 ? kk : k1;
        }
    }

    // ---- fp64 rescue for ambiguous argmins (rare) ----
    if (s2 - s1 < TAU) {
        double bd = 1e300; int bk = 1 << 30;
        #pragma unroll
        for (int ci = 0; ci < 3; ++ci) {
            int kk = (ci == 0) ? k1 : (ci == 1) ? k2 : ((s3 - s1 < TAU) ? k3 : -1);
            if (kk >= 0) {
                double dot = 0.0, w2d = 0.0;
                #pragma unroll
                for (int d = 0; d < DD; ++d) {
                    double wv = (double)w[d * KK + kk];
                    dot = fma((double)xr[d], wv, dot);
                    w2d = fma(wv, wv, w2d);
                }
                double scd = fma(-2.0, dot, w2d);
                if (scd < bd || (scd == bd && kk < bk)) { bd = scd; bk = kk; }
            }
        }
        k1 = bk;
    }

    // ---- outputs ----
    out_idx[loc] = (float)k1;                       // argmin as float
    #pragma unroll
    for (int d = 0; d < DD; ++d)
        out_res[base + (long)d * HWSZ] = w[d * KK + k1];  // gather (L2-hot row)
}

extern "C" void kernel_launch(void* const* d_in, const int* in_sizes, int n_in,
                              void* d_out, int out_size, void* d_ws, size_t ws_size,
                              hipStream_t stream) {
    const float* x = (const float*)d_in[0];
    const float* w = (const float*)d_in[1];
    float* out = (float*)d_out;
    float* out_res = out;                   // 32*64*64*64 = 8388608 floats
    float* out_idx = out + (NLOC * DD);     // 131072 floats (argmin)
    ne_kernel<<<NLOC / 256, 256, 0, stream>>>(x, w, out_res, out_idx);
}

// Round 5
// 127.970 us; speedup vs baseline: 3.7150x; 3.7150x over previous
//
#include <hip/hip_runtime.h>

// NearestEmbed via MFMA (Round 5).
// scores[loc,k] = ||w_k||^2 - 2 * dot(x_loc, w_k); argmin_k; gather.
// GEMM (131072x64)x(64x512) done with mfma_f32_16x16x32_bf16 using a
// 3-pass bf16 precision split (hi*hi + hi*lo + lo*hi, fp32 accum).
// Mapping: MFMA rows = k-codes, cols = locations -> per-location argmin
// reduces over 4 reg slots (in-register) + lanes {l^16, l^32} (2 shuffles).
// Top-2 tracking + fp64 rescue when gap < TAU (verified exact in R3).
//
// Block: 512 threads (8 waves), 256 locations (32/wave as 2 A-sets of 16).
// LDS: W staged once as bf16 hi/lo, XOR-swizzled for conflict-free b128.

typedef float  f32x4  __attribute__((ext_vector_type(4)));
typedef short  bf16x8 __attribute__((ext_vector_type(8)));

#define KK   512
#define DD   64
#define HWSZ 4096
#define NLOC (32*HWSZ)
#define LPB  256          // locations per block
#define TAU  1e-3f

static __device__ __forceinline__ short f2bf_rne(float f) {
    unsigned u = __float_as_uint(f);
    unsigned r = (u + 0x7FFFu + ((u >> 16) & 1u)) >> 16;
    return (short)r;
}

__global__ __launch_bounds__(512, 2)
void ne_mfma(const float* __restrict__ x, const float* __restrict__ w,
             float* __restrict__ out_res, float* __restrict__ out_idx) {
    __shared__ __align__(16) short wt_hi[KK*DD];   // 64 KB, swizzled
    __shared__ __align__(16) short wt_lo[KK*DD];   // 64 KB, swizzled
    __shared__ __align__(16) float w2s[KK];        // 2 KB
    __shared__ int k1s[LPB];                       // 1 KB

    const int tid  = threadIdx.x;
    const int lane = tid & 63;
    const int wv   = tid >> 6;       // wave 0..7
    const int col  = lane & 15;      // MFMA col (location within 16-set)
    const int lgr  = lane >> 4;      // lane group 0..3

    const int bloc0 = blockIdx.x * LPB;
    const int b     = bloc0 >> 12;
    const long xbase = (long)b * (DD*HWSZ);
    const int hw0   = bloc0 & 4095;

    char* wh_b = (char*)wt_hi;
    char* wl_b = (char*)wt_lo;

    // ---------- stage W -> LDS bf16 hi/lo (XOR-swizzled rows), w2 ----------
    {
        const int n = tid;           // 512 threads = 512 codebook rows (k)
        float w2 = 0.f;
        #pragma unroll
        for (int g = 0; g < 8; ++g) {
            bf16x8 hv, lv;
            #pragma unroll
            for (int j = 0; j < 8; ++j) {
                float v = w[(g*8 + j)*KK + n];
                w2 = fmaf(v, v, w2);
                unsigned bits = __float_as_uint(v);
                unsigned hb = bits & 0xFFFF0000u;
                hv[j] = (short)(hb >> 16);                       // truncated hi
                lv[j] = f2bf_rne(v - __uint_as_float(hb));       // residual lo
            }
            const int slot = g ^ (n & 7);
            *(bf16x8*)(wh_b + n*128 + slot*16) = hv;
            *(bf16x8*)(wl_b + n*128 + slot*16) = lv;
        }
        w2s[n] = w2;
    }

    // ---------- X fragments: 2 sets x 16 locations, bf16 hi/lo ----------
    const int wloc0 = bloc0 + wv * 32;
    bf16x8 Xh0[2], Xl0[2], Xh1[2], Xl1[2];   // [chunk] for set 0 / set 1
    #pragma unroll
    for (int s = 0; s < 2; ++s) {
        const int hw = (wloc0 + s*16 + col) & 4095;
        #pragma unroll
        for (int c = 0; c < 2; ++c) {
            #pragma unroll
            for (int j = 0; j < 8; ++j) {
                const int d = c*32 + lgr*8 + j;
                float v = x[xbase + (long)d*HWSZ + hw];
                unsigned bits = __float_as_uint(v);
                unsigned hb = bits & 0xFFFF0000u;
                short hj = (short)(hb >> 16);
                short lj = f2bf_rne(v - __uint_as_float(hb));
                if (s == 0) { Xh0[c][j] = hj; Xl0[c][j] = lj; }
                else        { Xh1[c][j] = hj; Xl1[c][j] = lj; }
            }
        }
    }

    __syncthreads();

    // ---------- main loop over 32 k-tiles ----------
    float m1[2][4], m2[2][4]; int i1[2][4], i2[2][4];
    #pragma unroll
    for (int s = 0; s < 2; ++s)
        #pragma unroll
        for (int r = 0; r < 4; ++r) { m1[s][r] = 3.4e38f; m2[s][r] = 3.4e38f; i1[s][r] = 0; i2[s][r] = 0; }

    #pragma unroll 2
    for (int t = 0; t < 32; ++t) {
        const int n = t*16 + col;                // W row (k) this lane supplies
        f32x4 acc0 = {0.f,0.f,0.f,0.f}, acc1 = {0.f,0.f,0.f,0.f};
        #pragma unroll
        for (int c = 0; c < 2; ++c) {
            const int off = (n*128 + (c*4 + lgr)*16) ^ ((n & 7) << 4);
            bf16x8 Wh = *(const bf16x8*)(wh_b + off);
            bf16x8 Wl = *(const bf16x8*)(wl_b + off);
            acc0 = __builtin_amdgcn_mfma_f32_16x16x32_bf16(Wl, Xh0[c], acc0, 0,0,0);
            acc0 = __builtin_amdgcn_mfma_f32_16x16x32_bf16(Wh, Xl0[c], acc0, 0,0,0);
            acc0 = __builtin_amdgcn_mfma_f32_16x16x32_bf16(Wh, Xh0[c], acc0, 0,0,0);
            acc1 = __builtin_amdgcn_mfma_f32_16x16x32_bf16(Wl, Xh1[c], acc1, 0,0,0);
            acc1 = __builtin_amdgcn_mfma_f32_16x16x32_bf16(Wh, Xl1[c], acc1, 0,0,0);
            acc1 = __builtin_amdgcn_mfma_f32_16x16x32_bf16(Wh, Xh1[c], acc1, 0,0,0);
        }
        const f32x4 w2v = *(const f32x4*)((const char*)w2s + t*64 + lgr*16);
        const int kb = t*16 + lgr*4;
        #pragma unroll
        for (int r = 0; r < 4; ++r) {
            {   // set 0: score of k=kb+r for location wloc0+col
                float sc = fmaf(-2.f, acc0[r], w2v[r]);
                bool c1 = sc < m1[0][r], c2 = sc < m2[0][r];
                m2[0][r] = c1 ? m1[0][r] : (c2 ? sc : m2[0][r]);
                i2[0][r] = c1 ? i1[0][r] : (c2 ? (kb+r) : i2[0][r]);
                m1[0][r] = c1 ? sc : m1[0][r];
                i1[0][r] = c1 ? (kb+r) : i1[0][r];
            }
            {   // set 1
                float sc = fmaf(-2.f, acc1[r], w2v[r]);
                bool c1 = sc < m1[1][r], c2 = sc < m2[1][r];
                m2[1][r] = c1 ? m1[1][r] : (c2 ? sc : m2[1][r]);
                i2[1][r] = c1 ? i1[1][r] : (c2 ? (kb+r) : i2[1][r]);
                m1[1][r] = c1 ? sc : m1[1][r];
                i1[1][r] = c1 ? (kb+r) : i1[1][r];
            }
        }
    }

    // ---------- reduce: 4 reg slots, then lanes l^16, l^32 ----------
    #pragma unroll
    for (int s = 0; s < 2; ++s) {
        float a1 = m1[s][0], a2 = m2[s][0]; int j1 = i1[s][0], j2 = i2[s][0];
        #pragma unroll
        for (int r = 1; r < 4; ++r) {
            float b1v = m1[s][r], b2v = m2[s][r]; int jb1 = i1[s][r], jb2 = i2[s][r];
            bool bw = (b1v < a1) || (b1v == a1 && jb1 < j1);
            float w1 = bw ? b1v : a1;  int wj1 = bw ? jb1 : j1;
            float lo = bw ? a1  : b1v; int loj = bw ? j1  : jb1;   // loser-first
            float ws = bw ? b2v : a2;  int wsj = bw ? jb2 : j2;    // winner-second
            bool sw = (lo < ws) || (lo == ws && loj < wsj);
            a1 = w1; j1 = wj1;
            a2 = sw ? lo : ws; j2 = sw ? loj : wsj;
        }
        #pragma unroll
        for (int msk = 16; msk <= 32; msk <<= 1) {
            float b1v = __shfl_xor(a1, msk, 64);
            int   jb1 = __shfl_xor(j1, msk, 64);
            float b2v = __shfl_xor(a2, msk, 64);
            int   jb2 = __shfl_xor(j2, msk, 64);
            bool bw = (b1v < a1) || (b1v == a1 && jb1 < j1);
            float w1 = bw ? b1v : a1;  int wj1 = bw ? jb1 : j1;
            float lo = bw ? a1  : b1v; int loj = bw ? j1  : jb1;
            float ws = bw ? b2v : a2;  int wsj = bw ? jb2 : j2;
            bool sw = (lo < ws) || (lo == ws && loj < wsj);
            a1 = w1; j1 = wj1;
            a2 = sw ? lo : ws; j2 = sw ? loj : wsj;
        }
        if (lane < 16) {
            const int loc = wloc0 + s*16 + lane;     // lane == col for lane<16
            int kf = j1;
            if (a2 - a1 < TAU) {                     // fp64 rescue (rare)
                const int hw = loc & 4095;
                double bd = 1e300; int bk = 1 << 30;
                for (int ci = 0; ci < 2; ++ci) {
                    int kk = ci ? j2 : j1;
                    double dot = 0.0, w2d = 0.0;
                    for (int d = 0; d < DD; ++d) {
                        double wvv = (double)w[(long)d*KK + kk];
                        dot = fma((double)x[xbase + (long)d*HWSZ + hw], wvv, dot);
                        w2d = fma(wvv, wvv, w2d);
                    }
                    double scd = fma(-2.0, dot, w2d);
                    if (scd < bd || (scd == bd && kk < bk)) { bd = scd; bk = kk; }
                }
                kf = bk;
            }
            k1s[loc - bloc0] = kf;
            out_idx[loc] = (float)kf;
        }
    }

    __syncthreads();

    // ---------- output 0: quantized = w[:, k1] scattered back ----------
    {
        const int loc = tid & 255;
        const int dp  = tid >> 8;            // 0 or 1
        const int kf  = k1s[loc];
        const long ob = xbase + hw0 + loc;
        #pragma unroll
        for (int i = 0; i < 32; ++i) {
            const int d = i*2 + dp;
            out_res[ob + (long)d*HWSZ] = w[(long)d*KK + kf];
        }
    }
}

extern "C" void kernel_launch(void* const* d_in, const int* in_sizes, int n_in,
                              void* d_out, int out_size, void* d_ws, size_t ws_size,
                              hipStream_t stream) {
    const float* x = (const float*)d_in[0];
    const float* w = (const float*)d_in[1];
    float* out = (float*)d_out;
    float* out_res = out;                   // 8388608 floats
    float* out_idx = out + (NLOC * DD);     // 131072 floats (argmin)
    ne_mfma<<<NLOC / LPB, 512, 0, stream>>>(x, w, out_res, out_idx);
}

// Round 7
// 122.909 us; speedup vs baseline: 3.8680x; 1.0412x over previous
//
#include <hip/hip_runtime.h>

// NearestEmbed via MFMA (Round 6).
// R5 (65us): 131KB LDS -> 1 block/CU; 512-thr blocks -> only 8 waves/CU and
// 512 blocks -> 2 serial rounds/CU. This round: 1024-thr blocks, LPB=512,
// grid=256 = exactly 1 block/CU, 16 waves/CU, staging paid once.
// Per-wave compute identical to verified R5 (absmax=0).

typedef float  f32x4  __attribute__((ext_vector_type(4)));
typedef short  bf16x8 __attribute__((ext_vector_type(8)));

#define KK   512
#define DD   64
#define HWSZ 4096
#define NLOC (32*HWSZ)
#define LPB  512          // locations per block
#define TAU  1e-3f

static __device__ __forceinline__ short f2bf_rne(float f) {
    unsigned u = __float_as_uint(f);
    unsigned r = (u + 0x7FFFu + ((u >> 16) & 1u)) >> 16;
    return (short)r;
}

__global__ __launch_bounds__(1024, 4)
void ne_mfma(const float* __restrict__ x, const float* __restrict__ w,
             float* __restrict__ out_res, float* __restrict__ out_idx) {
    __shared__ __align__(16) short wt_hi[KK*DD];   // 64 KB, swizzled
    __shared__ __align__(16) short wt_lo[KK*DD];   // 64 KB, swizzled
    __shared__ __align__(16) float w2s[KK];        // 2 KB
    __shared__ int k1s[LPB];                       // 2 KB

    const int tid  = threadIdx.x;
    const int lane = tid & 63;
    const int wv   = tid >> 6;       // wave 0..15
    const int col  = lane & 15;      // MFMA col (location within 16-set)
    const int lgr  = lane >> 4;      // lane group 0..3

    const int bloc0 = blockIdx.x * LPB;
    const int b     = bloc0 >> 12;
    const long xbase = (long)b * (DD*HWSZ);
    const int hw0   = bloc0 & 4095;

    char* wh_b = (char*)wt_hi;
    char* wl_b = (char*)wt_lo;

    // ---------- stage W -> LDS bf16 hi/lo (XOR-swizzled rows), w2 ----------
    // Thread-half h=0 stages d-chunks g=0..3 and computes full ||w_k||^2;
    // half h=1 stages g=4..7.
    {
        const int n = tid & 511;     // codebook row (k)
        const int h = tid >> 9;      // 0 or 1
        #pragma unroll
        for (int gg = 0; gg < 4; ++gg) {
            const int g = h*4 + gg;
            bf16x8 hv, lv;
            #pragma unroll
            for (int j = 0; j < 8; ++j) {
                float v = w[(g*8 + j)*KK + n];
                unsigned bits = __float_as_uint(v);
                unsigned hb = bits & 0xFFFF0000u;
                hv[j] = (short)(hb >> 16);                       // truncated hi
                lv[j] = f2bf_rne(v - __uint_as_float(hb));       // residual lo
            }
            const int slot = g ^ (n & 7);
            *(bf16x8*)(wh_b + n*128 + slot*16) = hv;
            *(bf16x8*)(wl_b + n*128 + slot*16) = lv;
        }
        if (h == 0) {
            float w2 = 0.f;
            #pragma unroll
            for (int d = 0; d < DD; ++d) {
                float v = w[d*KK + n];
                w2 = fmaf(v, v, w2);
            }
            w2s[n] = w2;
        }
    }

    // ---------- X fragments: 2 sets x 16 locations, bf16 hi/lo ----------
    const int wloc0 = bloc0 + wv * 32;
    bf16x8 Xh0[2], Xl0[2], Xh1[2], Xl1[2];   // [chunk] for set 0 / set 1
    #pragma unroll
    for (int s = 0; s < 2; ++s) {
        const int hw = (wloc0 + s*16 + col) & 4095;
        #pragma unroll
        for (int c = 0; c < 2; ++c) {
            #pragma unroll
            for (int j = 0; j < 8; ++j) {
                const int d = c*32 + lgr*8 + j;
                float v = x[xbase + (long)d*HWSZ + hw];
                unsigned bits = __float_as_uint(v);
                unsigned hb = bits & 0xFFFF0000u;
                short hj = (short)(hb >> 16);
                short lj = f2bf_rne(v - __uint_as_float(hb));
                if (s == 0) { Xh0[c][j] = hj; Xl0[c][j] = lj; }
                else        { Xh1[c][j] = hj; Xl1[c][j] = lj; }
            }
        }
    }

    __syncthreads();

    // ---------- main loop over 32 k-tiles ----------
    float m1[2][4], m2[2][4]; int i1[2][4], i2[2][4];
    #pragma unroll
    for (int s = 0; s < 2; ++s)
        #pragma unroll
        for (int r = 0; r < 4; ++r) { m1[s][r] = 3.4e38f; m2[s][r] = 3.4e38f; i1[s][r] = 0; i2[s][r] = 0; }

    #pragma unroll 2
    for (int t = 0; t < 32; ++t) {
        const int n = t*16 + col;                // W row (k) this lane supplies
        f32x4 acc0 = {0.f,0.f,0.f,0.f}, acc1 = {0.f,0.f,0.f,0.f};
        #pragma unroll
        for (int c = 0; c < 2; ++c) {
            const int off = (n*128 + (c*4 + lgr)*16) ^ ((n & 7) << 4);
            bf16x8 Wh = *(const bf16x8*)(wh_b + off);
            bf16x8 Wl = *(const bf16x8*)(wl_b + off);
            acc0 = __builtin_amdgcn_mfma_f32_16x16x32_bf16(Wl, Xh0[c], acc0, 0,0,0);
            acc0 = __builtin_amdgcn_mfma_f32_16x16x32_bf16(Wh, Xl0[c], acc0, 0,0,0);
            acc0 = __builtin_amdgcn_mfma_f32_16x16x32_bf16(Wh, Xh0[c], acc0, 0,0,0);
            acc1 = __builtin_amdgcn_mfma_f32_16x16x32_bf16(Wl, Xh1[c], acc1, 0,0,0);
            acc1 = __builtin_amdgcn_mfma_f32_16x16x32_bf16(Wh, Xl1[c], acc1, 0,0,0);
            acc1 = __builtin_amdgcn_mfma_f32_16x16x32_bf16(Wh, Xh1[c], acc1, 0,0,0);
        }
        const f32x4 w2v = *(const f32x4*)((const char*)w2s + t*64 + lgr*16);
        const int kb = t*16 + lgr*4;
        #pragma unroll
        for (int r = 0; r < 4; ++r) {
            {   // set 0: score of k=kb+r for location wloc0+col
                float sc = fmaf(-2.f, acc0[r], w2v[r]);
                bool c1 = sc < m1[0][r], c2 = sc < m2[0][r];
                m2[0][r] = c1 ? m1[0][r] : (c2 ? sc : m2[0][r]);
                i2[0][r] = c1 ? i1[0][r] : (c2 ? (kb+r) : i2[0][r]);
                m1[0][r] = c1 ? sc : m1[0][r];
                i1[0][r] = c1 ? (kb+r) : i1[0][r];
            }
            {   // set 1
                float sc = fmaf(-2.f, acc1[r], w2v[r]);
                bool c1 = sc < m1[1][r], c2 = sc < m2[1][r];
                m2[1][r] = c1 ? m1[1][r] : (c2 ? sc : m2[1][r]);
                i2[1][r] = c1 ? i1[1][r] : (c2 ? (kb+r) : i2[1][r]);
                m1[1][r] = c1 ? sc : m1[1][r];
                i1[1][r] = c1 ? (kb+r) : i1[1][r];
            }
        }
    }

    // ---------- reduce: 4 reg slots, then lanes l^16, l^32 ----------
    #pragma unroll
    for (int s = 0; s < 2; ++s) {
        float a1 = m1[s][0], a2 = m2[s][0]; int j1 = i1[s][0], j2 = i2[s][0];
        #pragma unroll
        for (int r = 1; r < 4; ++r) {
            float b1v = m1[s][r], b2v = m2[s][r]; int jb1 = i1[s][r], jb2 = i2[s][r];
            bool bw = (b1v < a1) || (b1v == a1 && jb1 < j1);
            float w1 = bw ? b1v : a1;  int wj1 = bw ? jb1 : j1;
            float lo = bw ? a1  : b1v; int loj = bw ? j1  : jb1;   // loser-first
            float ws = bw ? b2v : a2;  int wsj = bw ? jb2 : j2;    // winner-second
            bool sw = (lo < ws) || (lo == ws && loj < wsj);
            a1 = w1; j1 = wj1;
            a2 = sw ? lo : ws; j2 = sw ? loj : wsj;
        }
        #pragma unroll
        for (int msk = 16; msk <= 32; msk <<= 1) {
            float b1v = __shfl_xor(a1, msk, 64);
            int   jb1 = __shfl_xor(j1, msk, 64);
            float b2v = __shfl_xor(a2, msk, 64);
            int   jb2 = __shfl_xor(j2, msk, 64);
            bool bw = (b1v < a1) || (b1v == a1 && jb1 < j1);
            float w1 = bw ? b1v : a1;  int wj1 = bw ? jb1 : j1;
            float lo = bw ? a1  : b1v; int loj = bw ? j1  : jb1;
            float ws = bw ? b2v : a2;  int wsj = bw ? jb2 : j2;
            bool sw = (lo < ws) || (lo == ws && loj < wsj);
            a1 = w1; j1 = wj1;
            a2 = sw ? lo : ws; j2 = sw ? loj : wsj;
        }
        if (lane < 16) {
            const int loc = wloc0 + s*16 + lane;     // lane == col for lane<16
            int kf = j1;
            if (a2 - a1 < TAU) {                     // fp64 rescue (rare)
                const int hw = loc & 4095;
                double bd = 1e300; int bk = 1 << 30;
                for (int ci = 0; ci < 2; ++ci) {
                    int kk = ci ? j2 : j1;
                    double dot = 0.0, w2d = 0.0;
                    for (int d = 0; d < DD; ++d) {
                        double wvv = (double)w[(long)d*KK + kk];
                        dot = fma((double)x[xbase + (long)d*HWSZ + hw], wvv, dot);
                        w2d = fma(wvv, wvv, w2d);
                    }
                    double scd = fma(-2.0, dot, w2d);
                    if (scd < bd || (scd == bd && kk < bk)) { bd = scd; bk = kk; }
                }
                kf = bk;
            }
            k1s[loc - bloc0] = kf;
            out_idx[loc] = (float)kf;
        }
    }

    __syncthreads();

    // ---------- output 0: quantized = w[:, k1] scattered back ----------
    {
        const int loc = tid & 511;
        const int dp  = tid >> 9;            // 0 or 1
        const int kf  = k1s[loc];
        const long ob = xbase + hw0 + loc;
        #pragma unroll
        for (int i = 0; i < 32; ++i) {
            const int d = i*2 + dp;
            out_res[ob + (long)d*HWSZ] = w[(long)d*KK + kf];
        }
    }
}

extern "C" void kernel_launch(void* const* d_in, const int* in_sizes, int n_in,
                              void* d_out, int out_size, void* d_ws, size_t ws_size,
                              hipStream_t stream) {
    const float* x = (const float*)d_in[0];
    const float* w = (const float*)d_in[1];
    float* out = (float*)d_out;
    float* out_res = out;                   // 8388608 floats
    float* out_idx = out + (NLOC * DD);     // 131072 floats (argmin)
    ne_mfma<<<NLOC / LPB, 1024, 0, stream>>>(x, w, out_res, out_idx);
}